// Round 4
// baseline (58.206 us; speedup 1.0000x reference)
//
#include <hip/hip_runtime.h>
#include <math.h>

#define NS 21          // percept rows (index 0 unused, idx in [1,20])
#define NPAIR (NS*NS)  // 441 precomputed pairs

typedef int   int4v   __attribute__((ext_vector_type(4)));
typedef float float4v __attribute__((ext_vector_type(4)));
typedef float float2v __attribute__((ext_vector_type(2)));

// ---------- pass 1: build the 441-entry {s, s*log s} table (1 block) ----------
__global__ __launch_bounds__(512) void build_tab_kernel(
    const float* __restrict__ percept,  // (21, 3)
    const float* __restrict__ w,        // (3,)
    const float* __restrict__ rho_p,
    const float* __restrict__ beta_p,
    const float* __restrict__ tau_p,
    const float* __restrict__ gamma_p,
    float2v* __restrict__ tab_out)      // (441,)
{
    const float rho   = rho_p[0];
    const float beta  = beta_p[0];
    const float tau   = tau_p[0];
    const float gamma = gamma_p[0];
    const float w0 = w[0], w1 = w[1], w2 = w[2];
    const float inv_rho = 1.0f / rho;

    int e = threadIdx.x;
    if (e < NPAIR) {
        int q = e / NS;
        int r = e - q * NS;
        float dx = fabsf(percept[q * 3 + 0] - percept[r * 3 + 0]);
        float dy = fabsf(percept[q * 3 + 1] - percept[r * 3 + 1]);
        float dz = fabsf(percept[q * 3 + 2] - percept[r * 3 + 2]);
        float acc = w0 * powf(dx, rho) + w1 * powf(dy, rho) + w2 * powf(dz, rho);
        float d = powf(acc, inv_rho);
        float s = expf(-beta * powf(d, tau)) + gamma;
        float2v o; o.x = s; o.y = s * logf(s);
        tab_out[e] = o;
    }
}

// ---------- pass 2: per-row gather + softmax/entropy/rt ----------
__global__ __launch_bounds__(256) void rank_rt_kernel(
    const int*     __restrict__ idx,    // (nrows, 5)
    const float2v* __restrict__ tab_g,  // (441,) from pass 1
    const float*   __restrict__ upper_p,
    const float*   __restrict__ mid_p,
    const float*   __restrict__ rate_p,
    float* __restrict__ out,            // p: nrows*4, then rt: nrows
    int nrows)
{
    __shared__ float2v tab[NPAIR];

    // stream the 3.5 KB table into LDS (coalesced b64 loads, 2/thread)
    for (int e = threadIdx.x; e < NPAIR; e += 256)
        tab[e] = tab_g[e];

    const float upper = upper_p[0];
    const float mid   = mid_p[0];
    const float rate  = rate_p[0];
    __syncthreads();

    const size_t t    = (size_t)blockIdx.x * blockDim.x + threadIdx.x;
    const size_t row0 = t * 4;
    if (row0 >= (size_t)nrows) return;

    if (row0 + 4 <= (size_t)nrows) {
        const int4v* ip = reinterpret_cast<const int4v*>(idx + row0 * 5);
        int4v a0 = __builtin_nontemporal_load(ip + 0);
        int4v a1 = __builtin_nontemporal_load(ip + 1);
        int4v a2 = __builtin_nontemporal_load(ip + 2);
        int4v a3 = __builtin_nontemporal_load(ip + 3);
        int4v a4 = __builtin_nontemporal_load(ip + 4);
        const int v[20] = { a0.x, a0.y, a0.z, a0.w,
                            a1.x, a1.y, a1.z, a1.w,
                            a2.x, a2.y, a2.z, a2.w,
                            a3.x, a3.y, a3.z, a3.w,
                            a4.x, a4.y, a4.z, a4.w };
        float rt_arr[4];
        #pragma unroll
        for (int k = 0; k < 4; ++k) {
            const int qb = v[5 * k] * NS;
            float2v e0 = tab[qb + v[5 * k + 1]];
            float2v e1 = tab[qb + v[5 * k + 2]];
            float2v e2 = tab[qb + v[5 * k + 3]];
            float2v e3 = tab[qb + v[5 * k + 4]];

            float S = (e0.x + e1.x) + (e2.x + e3.x);
            float T = (e0.y + e1.y) + (e2.y + e3.y);
            float invS = __builtin_amdgcn_rcpf(S);

            float ent = __logf(S) - T * invS;   // -sum p log p
            rt_arr[k] = upper * __builtin_amdgcn_rcpf(1.0f + __expf(-rate * (ent - mid)));

            float4v p;
            p.x = e0.x * invS;
            p.y = e1.x * invS;
            p.z = e2.x * invS;
            p.w = e3.x * invS;
            __builtin_nontemporal_store(p, reinterpret_cast<float4v*>(out + (row0 + k) * 4));
        }
        float4v rt4; rt4.x = rt_arr[0]; rt4.y = rt_arr[1]; rt4.z = rt_arr[2]; rt4.w = rt_arr[3];
        __builtin_nontemporal_store(rt4, reinterpret_cast<float4v*>(out + (size_t)nrows * 4 + row0));
    } else {
        for (size_t row = row0; row < (size_t)nrows; ++row) {
            const size_t base = row * 5;
            int qb = idx[base] * NS;
            float2v e0 = tab[qb + idx[base + 1]];
            float2v e1 = tab[qb + idx[base + 2]];
            float2v e2 = tab[qb + idx[base + 3]];
            float2v e3 = tab[qb + idx[base + 4]];
            float S = (e0.x + e1.x) + (e2.x + e3.x);
            float T = (e0.y + e1.y) + (e2.y + e3.y);
            float invS = __builtin_amdgcn_rcpf(S);
            float ent = __logf(S) - T * invS;
            float rt = upper * __builtin_amdgcn_rcpf(1.0f + __expf(-rate * (ent - mid)));
            out[row * 4 + 0] = e0.x * invS;
            out[row * 4 + 1] = e1.x * invS;
            out[row * 4 + 2] = e2.x * invS;
            out[row * 4 + 3] = e3.x * invS;
            out[(size_t)nrows * 4 + row] = rt;
        }
    }
}

extern "C" void kernel_launch(void* const* d_in, const int* in_sizes, int n_in,
                              void* d_out, int out_size, void* d_ws, size_t ws_size,
                              hipStream_t stream) {
    const int*   idx     = (const int*)  d_in[0];
    const float* percept = (const float*)d_in[1];
    const float* w       = (const float*)d_in[2];
    const float* rho     = (const float*)d_in[3];
    const float* beta    = (const float*)d_in[4];
    const float* tau     = (const float*)d_in[5];
    const float* gamma   = (const float*)d_in[6];
    const float* upper   = (const float*)d_in[7];
    const float* mid     = (const float*)d_in[8];
    const float* rate    = (const float*)d_in[9];
    float* out = (float*)d_out;
    float2v* tab_ws = (float2v*)d_ws;   // 441 * 8 B = 3.5 KB scratch

    const int nrows = in_sizes[0] / 5;
    const int block = 256;
    const int quads = (nrows + 3) / 4;
    const int grid  = (quads + block - 1) / block;

    build_tab_kernel<<<1, 512, 0, stream>>>(percept, w, rho, beta, tau, gamma, tab_ws);
    rank_rt_kernel<<<grid, block, 0, stream>>>(idx, tab_ws, upper, mid, rate, out, nrows);
}

// Round 5
// 24.393 us; speedup vs baseline: 2.3862x; 2.3862x over previous
//
#include <hip/hip_runtime.h>
#include <math.h>

#define NS 21          // percept rows (index 0 unused, idx in [1,20])
#define NPAIR (NS*NS)  // 441 precomputed pairs

typedef int   int4v   __attribute__((ext_vector_type(4)));
typedef float float4v __attribute__((ext_vector_type(4)));
typedef float float2v __attribute__((ext_vector_type(2)));

#define LOG2E 1.4426950408889634f
#define LN2   0.6931471805599453f

// x >= 0 ; 0^r -> exp2(r * -inf) = 0, correct for r > 0
__device__ __forceinline__ float fast_pow(float x, float r) {
    return __builtin_amdgcn_exp2f(r * __builtin_amdgcn_logf(x));
}

__global__ __launch_bounds__(256) void rank_rt_kernel(
    const int*   __restrict__ idx,      // (nrows, 5)
    const float* __restrict__ percept,  // (21, 3)
    const float* __restrict__ w,        // (3,)
    const float* __restrict__ rho_p,
    const float* __restrict__ beta_p,
    const float* __restrict__ tau_p,
    const float* __restrict__ gamma_p,
    const float* __restrict__ upper_p,
    const float* __restrict__ mid_p,
    const float* __restrict__ rate_p,
    float* __restrict__ out,            // p: nrows*4, then rt: nrows
    int nrows)
{
    __shared__ float2v tab[NPAIR];      // {s, s*log(s)} per (q,r)

    // ---- per-block table build: cheap fast-math pow, ~2 entries/thread ----
    {
        const float rho   = rho_p[0];
        const float beta  = beta_p[0];
        const float tau   = tau_p[0];
        const float gamma = gamma_p[0];
        const float w0 = w[0], w1 = w[1], w2 = w[2];
        const float inv_rho = 1.0f / rho;
        for (int e = threadIdx.x; e < NPAIR; e += 256) {
            int q = e / NS;
            int r = e - q * NS;
            float dx = fabsf(percept[q * 3 + 0] - percept[r * 3 + 0]);
            float dy = fabsf(percept[q * 3 + 1] - percept[r * 3 + 1]);
            float dz = fabsf(percept[q * 3 + 2] - percept[r * 3 + 2]);
            float acc = w0 * fast_pow(dx, rho) + w1 * fast_pow(dy, rho)
                      + w2 * fast_pow(dz, rho);
            float d = fast_pow(acc, inv_rho);
            float s = __builtin_amdgcn_exp2f(-beta * LOG2E * fast_pow(d, tau)) + gamma;
            float2v o;
            o.x = s;
            o.y = s * (LN2 * __builtin_amdgcn_logf(s));
            tab[e] = o;
        }
    }
    const float upper = upper_p[0];
    const float mid   = mid_p[0];
    const float rate  = rate_p[0];
    __syncthreads();

    const int t     = blockIdx.x * 256 + threadIdx.x;
    const int NT    = gridDim.x * 256;
    const int quads = (nrows + 3) >> 2;

    const int q0 = t;
    const int q1 = t + NT;
    const bool has0 = q0 < quads;
    const bool has1 = q1 < quads;
    const bool full0 = has0 && ((q0 + 1) * 4 <= nrows);
    const bool full1 = has1 && ((q1 + 1) * 4 <= nrows);

    // ---- issue ALL global loads upfront (10 independent int4) ----
    int4v a[5], b[5];
    if (full0) {
        const int4v* ip = reinterpret_cast<const int4v*>(idx + (size_t)q0 * 20);
        a[0] = ip[0]; a[1] = ip[1]; a[2] = ip[2]; a[3] = ip[3]; a[4] = ip[4];
    }
    if (full1) {
        const int4v* ip = reinterpret_cast<const int4v*>(idx + (size_t)q1 * 20);
        b[0] = ip[0]; b[1] = ip[1]; b[2] = ip[2]; b[3] = ip[3]; b[4] = ip[4];
    }

    #pragma unroll
    for (int which = 0; which < 2; ++which) {
        const int q = which ? q1 : q0;
        const bool full = which ? full1 : full0;
        const bool has  = which ? has1 : has0;
        if (full) {
            const int4v* A = which ? b : a;
            const int v[20] = { A[0].x, A[0].y, A[0].z, A[0].w,
                                A[1].x, A[1].y, A[1].z, A[1].w,
                                A[2].x, A[2].y, A[2].z, A[2].w,
                                A[3].x, A[3].y, A[3].z, A[3].w,
                                A[4].x, A[4].y, A[4].z, A[4].w };
            const size_t row0 = (size_t)q * 4;
            float rt_arr[4];
            #pragma unroll
            for (int k = 0; k < 4; ++k) {
                const int qb = v[5 * k] * NS;
                float2v e0 = tab[qb + v[5 * k + 1]];
                float2v e1 = tab[qb + v[5 * k + 2]];
                float2v e2 = tab[qb + v[5 * k + 3]];
                float2v e3 = tab[qb + v[5 * k + 4]];

                float S = (e0.x + e1.x) + (e2.x + e3.x);
                float T = (e0.y + e1.y) + (e2.y + e3.y);
                float invS = __builtin_amdgcn_rcpf(S);

                float ent = LN2 * __builtin_amdgcn_logf(S) - T * invS;
                float z   = -rate * (ent - mid);
                rt_arr[k] = upper * __builtin_amdgcn_rcpf(
                                1.0f + __builtin_amdgcn_exp2f(z * LOG2E));

                float4v p;
                p.x = e0.x * invS;
                p.y = e1.x * invS;
                p.z = e2.x * invS;
                p.w = e3.x * invS;
                *reinterpret_cast<float4v*>(out + (row0 + k) * 4) = p;
            }
            float4v rt4;
            rt4.x = rt_arr[0]; rt4.y = rt_arr[1]; rt4.z = rt_arr[2]; rt4.w = rt_arr[3];
            *reinterpret_cast<float4v*>(out + (size_t)nrows * 4 + row0) = rt4;
        } else if (has) {
            // tail quad: scalar path
            const size_t row_lo = (size_t)q * 4;
            for (size_t row = row_lo; row < (size_t)nrows; ++row) {
                const size_t base = row * 5;
                int qb = idx[base] * NS;
                float2v e0 = tab[qb + idx[base + 1]];
                float2v e1 = tab[qb + idx[base + 2]];
                float2v e2 = tab[qb + idx[base + 3]];
                float2v e3 = tab[qb + idx[base + 4]];
                float S = (e0.x + e1.x) + (e2.x + e3.x);
                float T = (e0.y + e1.y) + (e2.y + e3.y);
                float invS = __builtin_amdgcn_rcpf(S);
                float ent = LN2 * __builtin_amdgcn_logf(S) - T * invS;
                float z   = -rate * (ent - mid);
                float rt  = upper * __builtin_amdgcn_rcpf(
                                1.0f + __builtin_amdgcn_exp2f(z * LOG2E));
                out[row * 4 + 0] = e0.x * invS;
                out[row * 4 + 1] = e1.x * invS;
                out[row * 4 + 2] = e2.x * invS;
                out[row * 4 + 3] = e3.x * invS;
                out[(size_t)nrows * 4 + row] = rt;
            }
        }
    }
}

extern "C" void kernel_launch(void* const* d_in, const int* in_sizes, int n_in,
                              void* d_out, int out_size, void* d_ws, size_t ws_size,
                              hipStream_t stream) {
    const int*   idx     = (const int*)  d_in[0];
    const float* percept = (const float*)d_in[1];
    const float* w       = (const float*)d_in[2];
    const float* rho     = (const float*)d_in[3];
    const float* beta    = (const float*)d_in[4];
    const float* tau     = (const float*)d_in[5];
    const float* gamma   = (const float*)d_in[6];
    const float* upper   = (const float*)d_in[7];
    const float* mid     = (const float*)d_in[8];
    const float* rate    = (const float*)d_in[9];
    float* out = (float*)d_out;

    const int nrows = in_sizes[0] / 5;
    const int quads = (nrows + 3) / 4;
    const int block = 256;
    // 2 quads (8 rows) per thread -> half the blocks, double the per-wave MLP
    const int threads_needed = (quads + 1) / 2;
    const int grid = (threads_needed + block - 1) / block;

    rank_rt_kernel<<<grid, block, 0, stream>>>(
        idx, percept, w, rho, beta, tau, gamma, upper, mid, rate, out, nrows);
}

// Round 6
// 22.282 us; speedup vs baseline: 2.6123x; 1.0948x over previous
//
#include <hip/hip_runtime.h>
#include <math.h>

#define NS 21          // percept rows (index 0 unused, idx in [1,20])
#define NPAIR (NS*NS)  // 441 precomputed pairs

typedef int   int4v   __attribute__((ext_vector_type(4)));
typedef float float4v __attribute__((ext_vector_type(4)));
typedef float float2v __attribute__((ext_vector_type(2)));

#define LOG2E 1.4426950408889634f
#define LN2   0.6931471805599453f

// x >= 0 ; 0^r -> exp2(r * -inf) = 0, correct for r > 0
__device__ __forceinline__ float fast_pow(float x, float r) {
    return __builtin_amdgcn_exp2f(r * __builtin_amdgcn_logf(x));
}

__global__ __launch_bounds__(256) void rank_rt_kernel(
    const int*   __restrict__ idx,      // (nrows, 5)
    const float* __restrict__ percept,  // (21, 3)
    const float* __restrict__ w,        // (3,)
    const float* __restrict__ rho_p,
    const float* __restrict__ beta_p,
    const float* __restrict__ tau_p,
    const float* __restrict__ gamma_p,
    const float* __restrict__ upper_p,
    const float* __restrict__ mid_p,
    const float* __restrict__ rate_p,
    float* __restrict__ out,            // p: nrows*4, then rt: nrows
    int nrows)
{
    __shared__ float2v tab[NPAIR];      // {s, s*log(s)} per (q,r)

    // ---- per-block table build: fast-math pow, ~2 entries/thread ----
    {
        const float rho   = rho_p[0];
        const float beta  = beta_p[0];
        const float tau   = tau_p[0];
        const float gamma = gamma_p[0];
        const float w0 = w[0], w1 = w[1], w2 = w[2];
        const float inv_rho = 1.0f / rho;
        for (int e = threadIdx.x; e < NPAIR; e += 256) {
            int q = e / NS;
            int r = e - q * NS;
            float dx = fabsf(percept[q * 3 + 0] - percept[r * 3 + 0]);
            float dy = fabsf(percept[q * 3 + 1] - percept[r * 3 + 1]);
            float dz = fabsf(percept[q * 3 + 2] - percept[r * 3 + 2]);
            float acc = w0 * fast_pow(dx, rho) + w1 * fast_pow(dy, rho)
                      + w2 * fast_pow(dz, rho);
            float d = fast_pow(acc, inv_rho);
            float s = __builtin_amdgcn_exp2f(-beta * LOG2E * fast_pow(d, tau)) + gamma;
            float2v o;
            o.x = s;
            o.y = s * (LN2 * __builtin_amdgcn_logf(s));
            tab[e] = o;
        }
    }
    const float upper = upper_p[0];
    const float mid   = mid_p[0];
    const float rate  = rate_p[0];
    __syncthreads();

    const int q = blockIdx.x * 256 + threadIdx.x;   // one quad (4 rows) per thread
    const int quads = (nrows + 3) >> 2;
    if (q >= quads) return;

    if ((q + 1) * 4 <= nrows) {
        // 4 rows: 20 ints = 5 x int4, all issued upfront
        const int4v* ip = reinterpret_cast<const int4v*>(idx + (size_t)q * 20);
        int4v a0 = ip[0], a1 = ip[1], a2 = ip[2], a3 = ip[3], a4 = ip[4];
        const int v[20] = { a0.x, a0.y, a0.z, a0.w,
                            a1.x, a1.y, a1.z, a1.w,
                            a2.x, a2.y, a2.z, a2.w,
                            a3.x, a3.y, a3.z, a3.w,
                            a4.x, a4.y, a4.z, a4.w };
        const size_t row0 = (size_t)q * 4;
        float rt_arr[4];
        #pragma unroll
        for (int k = 0; k < 4; ++k) {
            const int qb = v[5 * k] * NS;
            float2v e0 = tab[qb + v[5 * k + 1]];
            float2v e1 = tab[qb + v[5 * k + 2]];
            float2v e2 = tab[qb + v[5 * k + 3]];
            float2v e3 = tab[qb + v[5 * k + 4]];

            float S = (e0.x + e1.x) + (e2.x + e3.x);
            float T = (e0.y + e1.y) + (e2.y + e3.y);
            float invS = __builtin_amdgcn_rcpf(S);

            float ent = LN2 * __builtin_amdgcn_logf(S) - T * invS;
            float z   = -rate * (ent - mid);
            rt_arr[k] = upper * __builtin_amdgcn_rcpf(
                            1.0f + __builtin_amdgcn_exp2f(z * LOG2E));

            float4v p;
            p.x = e0.x * invS;
            p.y = e1.x * invS;
            p.z = e2.x * invS;
            p.w = e3.x * invS;
            *reinterpret_cast<float4v*>(out + (row0 + k) * 4) = p;
        }
        float4v rt4;
        rt4.x = rt_arr[0]; rt4.y = rt_arr[1]; rt4.z = rt_arr[2]; rt4.w = rt_arr[3];
        *reinterpret_cast<float4v*>(out + (size_t)nrows * 4 + row0) = rt4;
    } else {
        // tail quad (nrows % 4 != 0): scalar path
        for (size_t row = (size_t)q * 4; row < (size_t)nrows; ++row) {
            const size_t base = row * 5;
            int qb = idx[base] * NS;
            float2v e0 = tab[qb + idx[base + 1]];
            float2v e1 = tab[qb + idx[base + 2]];
            float2v e2 = tab[qb + idx[base + 3]];
            float2v e3 = tab[qb + idx[base + 4]];
            float S = (e0.x + e1.x) + (e2.x + e3.x);
            float T = (e0.y + e1.y) + (e2.y + e3.y);
            float invS = __builtin_amdgcn_rcpf(S);
            float ent = LN2 * __builtin_amdgcn_logf(S) - T * invS;
            float z   = -rate * (ent - mid);
            float rt  = upper * __builtin_amdgcn_rcpf(
                            1.0f + __builtin_amdgcn_exp2f(z * LOG2E));
            out[row * 4 + 0] = e0.x * invS;
            out[row * 4 + 1] = e1.x * invS;
            out[row * 4 + 2] = e2.x * invS;
            out[row * 4 + 3] = e3.x * invS;
            out[(size_t)nrows * 4 + row] = rt;
        }
    }
}

extern "C" void kernel_launch(void* const* d_in, const int* in_sizes, int n_in,
                              void* d_out, int out_size, void* d_ws, size_t ws_size,
                              hipStream_t stream) {
    const int*   idx     = (const int*)  d_in[0];
    const float* percept = (const float*)d_in[1];
    const float* w       = (const float*)d_in[2];
    const float* rho     = (const float*)d_in[3];
    const float* beta    = (const float*)d_in[4];
    const float* tau     = (const float*)d_in[5];
    const float* gamma   = (const float*)d_in[6];
    const float* upper   = (const float*)d_in[7];
    const float* mid     = (const float*)d_in[8];
    const float* rate    = (const float*)d_in[9];
    float* out = (float*)d_out;

    const int nrows = in_sizes[0] / 5;
    const int quads = (nrows + 3) / 4;      // 1 quad (4 rows) per thread
    const int block = 256;
    const int grid  = (quads + block - 1) / block;   // 2048 blocks at B=2M

    rank_rt_kernel<<<grid, block, 0, stream>>>(
        idx, percept, w, rho, beta, tau, gamma, upper, mid, rate, out, nrows);
}